// Round 1
// baseline (2346.211 us; speedup 1.0000x reference)
//
#include <hip/hip_runtime.h>
#include <hip/hip_bf16.h>
#include <stdint.h>

#define PS 56
#define S_ 3136
#define DIM 128
#define NTOK 200704   // 64 * 3136

__device__ __forceinline__ float bflo(uint32_t u){ return __uint_as_float(u << 16); }
__device__ __forceinline__ float bfhi(uint32_t u){ return __uint_as_float(u & 0xffff0000u); }
__device__ __forceinline__ uint32_t bfpack(float a, float b){
  uint32_t ua = __float_as_uint(a); ua = (ua + 0x7fffu + ((ua >> 16) & 1u)) >> 16;
  uint32_t ub = __float_as_uint(b); ub = (ub + 0x7fffu + ((ub >> 16) & 1u)) & 0xffff0000u;
  return ua | ub;
}
__device__ __forceinline__ uint16_t bf16of(float a){
  uint32_t ua = __float_as_uint(a);
  return (uint16_t)((ua + 0x7fffu + ((ua >> 16) & 1u)) >> 16);
}

// windowed row r = b*3136 + w*49 + p  ->  flat token index with optional cyclic shift
__device__ __forceinline__ int win_map(int r, int shift) {
  int b = r / S_;
  int rem = r - b * S_;
  int w = rem / 49;
  int p = rem - w * 49;
  int i = p / 7, j = p - i * 7;
  int wr = w >> 3, wc = w & 7;
  int row = wr * 7 + i + shift; if (row >= PS) row -= PS;
  int col = wc * 7 + j + shift; if (col >= PS) col -= PS;
  return b * S_ + row * PS + col;
}

// per-token LayerNorm stats: mean and rstd. one wave per token.
__global__ __launch_bounds__(256) void stats_k(const float* __restrict__ X, float* __restrict__ st) {
  int t = blockIdx.x * 4 + (threadIdx.x >> 6);
  int lane = threadIdx.x & 63;
  float2 v = *(const float2*)(X + (size_t)t * DIM + lane * 2);
  float s = v.x + v.y, sq = v.x * v.x + v.y * v.y;
  #pragma unroll
  for (int o = 32; o; o >>= 1) { s += __shfl_xor(s, o); sq += __shfl_xor(sq, o); }
  if (lane == 0) {
    float mu = s * (1.0f / 128.0f);
    float var = sq * (1.0f / 128.0f) - mu * mu;
    st[2 * t] = mu;
    st[2 * t + 1] = rsqrtf(var + 1e-5f);
  }
}

// C[M x N] = A'[M x 128] * W^T[N x 128] + bias (+ residual), with A-gather / C-scatter modes.
// IN_MODE 0: A = LN(x[map]) from f32 x + stats.  IN_MODE 1: A = contiguous bf16 rows.
// IN_SHIFT / OUT_SHIFT: -1 = identity row map, else window map with that cyclic shift.
constexpr int TM = 64, TN = 128, KC = 64, KSTR = KC + 4;

template<int IN_MODE, int IN_SHIFT, int OUT_SHIFT, bool RES, bool OUT_BF16>
__global__ __launch_bounds__(256) void gemm_k(
    const void* __restrict__ Asrc, const float* __restrict__ st,
    const float* __restrict__ lng, const float* __restrict__ lnb,
    const float* __restrict__ W, const float* __restrict__ bias,
    const float* __restrict__ Rsrc, void* __restrict__ Out, int Ncols)
{
  __shared__ float As[TM][KSTR];
  __shared__ float Ws[TN][KSTR];
  const int tid = threadIdx.x;
  const int tx = tid & 15, ty = tid >> 4;
  const int ty4 = ty * 4;
  const int mtile = blockIdx.y * TM;
  const int ntile = blockIdx.x * TN;
  float acc[4][8];
  #pragma unroll
  for (int r = 0; r < 4; ++r)
    #pragma unroll
    for (int c = 0; c < 8; ++c) acc[r][c] = 0.f;

  for (int kc = 0; kc < DIM; kc += KC) {
    // stage A tile (64 rows x 64 k), coalesced global read, row-major LDS
    #pragma unroll
    for (int it = 0; it < 4; ++it) {
      int idx = tid + it * 256;
      int m = idx >> 4;
      int k4 = (idx & 15) << 2;
      int gm = mtile + m;
      float4 a;
      if constexpr (IN_MODE == 0) {
        int src = (IN_SHIFT < 0) ? gm : win_map(gm, IN_SHIFT);
        a = *(const float4*)((const float*)Asrc + (size_t)src * DIM + kc + k4);
        float mu = st[2 * src], rs = st[2 * src + 1];
        int k = kc + k4;
        a.x = (a.x - mu) * rs * lng[k]     + lnb[k];
        a.y = (a.y - mu) * rs * lng[k + 1] + lnb[k + 1];
        a.z = (a.z - mu) * rs * lng[k + 2] + lnb[k + 2];
        a.w = (a.w - mu) * rs * lng[k + 3] + lnb[k + 3];
      } else {
        const uint32_t* ap = (const uint32_t*)((const uint16_t*)Asrc + (size_t)gm * DIM + kc + k4);
        uint32_t u0 = ap[0], u1 = ap[1];
        a.x = bflo(u0); a.y = bfhi(u0); a.z = bflo(u1); a.w = bfhi(u1);
      }
      *(float4*)&As[m][k4] = a;
    }
    // stage W tile (TN rows x 64 k)
    #pragma unroll
    for (int it = 0; it < 8; ++it) {
      int idx = tid + it * 256;
      int n = idx >> 4;
      int k4 = (idx & 15) << 2;
      float4 w = *(const float4*)(W + (size_t)(ntile + n) * DIM + kc + k4);
      *(float4*)&Ws[n][k4] = w;
    }
    __syncthreads();
    #pragma unroll 4
    for (int k = 0; k < KC; k += 2) {
      float2 a0 = *(const float2*)&As[ty4 + 0][k];
      float2 a1 = *(const float2*)&As[ty4 + 1][k];
      float2 a2 = *(const float2*)&As[ty4 + 2][k];
      float2 a3 = *(const float2*)&As[ty4 + 3][k];
      #pragma unroll
      for (int c = 0; c < 8; ++c) {
        float2 w = *(const float2*)&Ws[tx + 16 * c][k];
        acc[0][c] = fmaf(a0.x, w.x, acc[0][c]);
        acc[1][c] = fmaf(a1.x, w.x, acc[1][c]);
        acc[2][c] = fmaf(a2.x, w.x, acc[2][c]);
        acc[3][c] = fmaf(a3.x, w.x, acc[3][c]);
        acc[0][c] = fmaf(a0.y, w.y, acc[0][c]);
        acc[1][c] = fmaf(a1.y, w.y, acc[1][c]);
        acc[2][c] = fmaf(a2.y, w.y, acc[2][c]);
        acc[3][c] = fmaf(a3.y, w.y, acc[3][c]);
      }
    }
    __syncthreads();
  }
  float bb[8];
  #pragma unroll
  for (int c = 0; c < 8; ++c) bb[c] = bias[ntile + tx + 16 * c];
  #pragma unroll
  for (int r = 0; r < 4; ++r) {
    int gm = mtile + ty4 + r;
    int orow = (OUT_SHIFT < 0) ? gm : win_map(gm, OUT_SHIFT);
    #pragma unroll
    for (int c = 0; c < 8; ++c) {
      int gn = ntile + tx + 16 * c;
      float v = acc[r][c] + bb[c];
      if constexpr (RES) v += Rsrc[(size_t)orow * DIM + gn];
      if constexpr (OUT_BF16) ((uint16_t*)Out)[(size_t)gm * Ncols + gn] = bf16of(v);
      else                    ((float*)Out)[(size_t)orow * (size_t)Ncols + gn] = v;
    }
  }
}

// one wave per (window, head). q + scores + out in registers, k/v in LDS (f32).
__global__ __launch_bounds__(64) void attn_k(const uint32_t* __restrict__ qkv32,
                                             const float* __restrict__ tbl,
                                             uint32_t* __restrict__ aw32)
{
  const int bid = blockIdx.x;
  const int w = bid >> 2, h = bid & 3;
  const int base = w * 49;
  const int lane = threadIdx.x;
  __shared__ float k_s[49 * 32];
  __shared__ float v_s[49 * 32];
  for (int p = lane; p < 784; p += 64) {
    int t = p >> 4, c2 = p & 15;
    size_t rowoff = (size_t)(base + t) * 192;   // 384 bf16 = 192 dwords per row
    uint32_t uk = qkv32[rowoff + 64  + h * 16 + c2];
    uint32_t uv = qkv32[rowoff + 128 + h * 16 + c2];
    k_s[t * 32 + 2 * c2]     = bflo(uk);
    k_s[t * 32 + 2 * c2 + 1] = bfhi(uk);
    v_s[t * 32 + 2 * c2]     = bflo(uv);
    v_s[t * 32 + 2 * c2 + 1] = bfhi(uv);
  }
  const int i = (lane < 49) ? lane : 48;
  float q[32];
  {
    const uint32_t* qrow = qkv32 + (size_t)(base + i) * 192 + h * 16;
    #pragma unroll
    for (int c2 = 0; c2 < 16; ++c2) {
      uint32_t u = qrow[c2];
      q[2 * c2]     = bflo(u) * 0.17677669529663689f;   // 1/sqrt(32)
      q[2 * c2 + 1] = bfhi(u) * 0.17677669529663689f;
    }
  }
  __syncthreads();
  const int yi = i / 7, xi = i - yi * 7;
  float s[49];
  #pragma unroll
  for (int j = 0; j < 49; ++j) {
    const int yj = j / 7, xj = j - yj * 7;   // j is a compile-time constant (full unroll)
    const float* kr = &k_s[j * 32];
    float a0 = 0.f, a1 = 0.f, a2 = 0.f, a3 = 0.f;
    #pragma unroll
    for (int c = 0; c < 32; c += 4) {
      float4 kk = *(const float4*)(kr + c);
      a0 = fmaf(q[c],     kk.x, a0);
      a1 = fmaf(q[c + 1], kk.y, a1);
      a2 = fmaf(q[c + 2], kk.z, a2);
      a3 = fmaf(q[c + 3], kk.w, a3);
    }
    int ridx = (yi - yj + 6) * 13 + (xi - xj + 6);
    s[j] = (a0 + a1) + (a2 + a3) + tbl[ridx * 4 + h];
  }
  // shift-mask adds (1-eq)*1e-9: numerically irrelevant, dropped.
  float mx = s[0];
  #pragma unroll
  for (int j = 1; j < 49; ++j) mx = fmaxf(mx, s[j]);
  float sum = 0.f;
  #pragma unroll
  for (int j = 0; j < 49; ++j) { s[j] = __expf(s[j] - mx); sum += s[j]; }
  float inv = 1.0f / sum;
  float o[32];
  #pragma unroll
  for (int c = 0; c < 32; ++c) o[c] = 0.f;
  #pragma unroll
  for (int j = 0; j < 49; ++j) {
    float sj = s[j] * inv;
    const float* vr = &v_s[j * 32];
    #pragma unroll
    for (int c = 0; c < 32; c += 4) {
      float4 vv = *(const float4*)(vr + c);
      o[c]     = fmaf(sj, vv.x, o[c]);
      o[c + 1] = fmaf(sj, vv.y, o[c + 1]);
      o[c + 2] = fmaf(sj, vv.z, o[c + 2]);
      o[c + 3] = fmaf(sj, vv.w, o[c + 3]);
    }
  }
  if (lane < 49) {
    uint32_t* dst = aw32 + (size_t)(base + i) * 64 + h * 16;
    #pragma unroll
    for (int c2 = 0; c2 < 16; ++c2) dst[c2] = bfpack(o[2 * c2], o[2 * c2 + 1]);
  }
}

extern "C" void kernel_launch(void* const* d_in, const int* in_sizes, int n_in,
                              void* d_out, int out_size, void* d_ws, size_t ws_size,
                              hipStream_t stream) {
  const float* x0    = (const float*)d_in[0];
  const float* ln1g  = (const float*)d_in[1];
  const float* ln1b  = (const float*)d_in[2];
  const float* wqkv1 = (const float*)d_in[3];
  const float* bqkv1 = (const float*)d_in[4];
  const float* wo1   = (const float*)d_in[5];
  const float* bo1   = (const float*)d_in[6];
  const float* tbl1  = (const float*)d_in[7];
  const float* ln2g  = (const float*)d_in[8];
  const float* ln2b  = (const float*)d_in[9];
  const float* wm1   = (const float*)d_in[10];
  const float* bm1   = (const float*)d_in[11];
  const float* ln3g  = (const float*)d_in[12];
  const float* ln3b  = (const float*)d_in[13];
  const float* wqkv2 = (const float*)d_in[14];
  const float* bqkv2 = (const float*)d_in[15];
  const float* wo2   = (const float*)d_in[16];
  const float* bo2   = (const float*)d_in[17];
  const float* tbl2  = (const float*)d_in[18];
  const float* ln4g  = (const float*)d_in[19];
  const float* ln4b  = (const float*)d_in[20];
  const float* wm2   = (const float*)d_in[21];
  const float* bm2   = (const float*)d_in[22];

  char* ws = (char*)d_ws;
  size_t off = 0;
  float* st = (float*)(ws + off);         off += (size_t)NTOK * 2 * sizeof(float);      // 1.6 MB
  off = (off + 255) & ~(size_t)255;
  uint16_t* qkvb = (uint16_t*)(ws + off); off += (size_t)NTOK * 384 * sizeof(uint16_t); // 154 MB
  uint16_t* awb  = (uint16_t*)(ws + off); off += (size_t)NTOK * 128 * sizeof(uint16_t); // 51 MB
  float* x2      = (float*)(ws + off);    off += (size_t)NTOK * 128 * sizeof(float);    // 103 MB
  if (ws_size < off) return;  // clean fail rather than OOB corruption
  float* x1 = (float*)d_out;  // x1 lives in d_out until the final GEMM overwrites it

  dim3 blk(256);
  dim3 sgrid(NTOK / 4);
  dim3 g3(3, 3136), g1(1, 3136);
  dim3 agrid(16384);

  // block 1: W-MSA
  stats_k<<<sgrid, blk, 0, stream>>>(x0, st);
  gemm_k<0, 0, -1, false, true><<<g3, blk, 0, stream>>>(x0, st, ln1g, ln1b, wqkv1, bqkv1, nullptr, qkvb, 384);
  attn_k<<<agrid, dim3(64), 0, stream>>>((const uint32_t*)qkvb, tbl1, (uint32_t*)awb);
  // block-1 un-window is a plain reshape -> identity row map; residual = x0 flat
  gemm_k<1, -1, -1, true, false><<<g1, blk, 0, stream>>>(awb, nullptr, nullptr, nullptr, wo1, bo1, x0, x1, 128);
  // mlp1
  stats_k<<<sgrid, blk, 0, stream>>>(x1, st);
  gemm_k<0, -1, -1, true, false><<<g1, blk, 0, stream>>>(x1, st, ln2g, ln2b, wm1, bm1, x1, x2, 128);
  // block 2: SW-MSA (roll -3 on input, proper un-window + roll +3 on output)
  stats_k<<<sgrid, blk, 0, stream>>>(x2, st);
  gemm_k<0, 3, -1, false, true><<<g3, blk, 0, stream>>>(x2, st, ln3g, ln3b, wqkv2, bqkv2, nullptr, qkvb, 384);
  attn_k<<<agrid, dim3(64), 0, stream>>>((const uint32_t*)qkvb, tbl2, (uint32_t*)awb);
  gemm_k<1, -1, 3, true, false><<<g1, blk, 0, stream>>>(awb, nullptr, nullptr, nullptr, wo2, bo2, x2, x2, 128);
  // mlp2 (final residual dropped by source)
  stats_k<<<sgrid, blk, 0, stream>>>(x2, st);
  gemm_k<0, -1, -1, false, false><<<g1, blk, 0, stream>>>(x2, st, ln4g, ln4b, wm2, bm2, nullptr, d_out, 128);
}

// Round 5
// 2100.313 us; speedup vs baseline: 1.1171x; 1.1171x over previous
//
#include <hip/hip_runtime.h>
#include <hip/hip_bf16.h>
#include <stdint.h>

#define PS 56
#define S_ 3136
#define DIM 128
#define NTOK 200704   // 64 * 3136

typedef __attribute__((ext_vector_type(8))) short short8;
typedef __attribute__((ext_vector_type(4))) float f32x4;

__device__ __forceinline__ float bflo(uint32_t u){ return __uint_as_float(u << 16); }
__device__ __forceinline__ float bfhi(uint32_t u){ return __uint_as_float(u & 0xffff0000u); }
__device__ __forceinline__ uint32_t bfpack(float a, float b){
  uint32_t ua = __float_as_uint(a); ua = (ua + 0x7fffu + ((ua >> 16) & 1u)) >> 16;
  uint32_t ub = __float_as_uint(b); ub = (ub + 0x7fffu + ((ub >> 16) & 1u)) & 0xffff0000u;
  return ua | ub;
}
__device__ __forceinline__ uint16_t bf16of(float a){
  uint32_t ua = __float_as_uint(a);
  return (uint16_t)((ua + 0x7fffu + ((ua >> 16) & 1u)) >> 16);
}

__device__ __forceinline__ int win_map(int r, int shift) {
  int b = r / S_;
  int rem = r - b * S_;
  int w = rem / 49;
  int p = rem - w * 49;
  int i = p / 7, j = p - i * 7;
  int wr = w >> 3, wc = w & 7;
  int row = wr * 7 + i + shift; if (row >= PS) row -= PS;
  int col = wc * 7 + j + shift; if (col >= PS) col -= PS;
  return b * S_ + row * PS + col;
}

__global__ __launch_bounds__(256) void stats_k(const float* __restrict__ X, float* __restrict__ st) {
  int t = blockIdx.x * 4 + (threadIdx.x >> 6);
  int lane = threadIdx.x & 63;
  float2 v = *(const float2*)(X + (size_t)t * DIM + lane * 2);
  float s = v.x + v.y, sq = v.x * v.x + v.y * v.y;
  #pragma unroll
  for (int o = 32; o; o >>= 1) { s += __shfl_xor(s, o); sq += __shfl_xor(sq, o); }
  if (lane == 0) {
    float mu = s * (1.0f / 128.0f);
    float var = sq * (1.0f / 128.0f) - mu * mu;
    st[2 * t] = mu;
    st[2 * t + 1] = rsqrtf(var + 1e-5f);
  }
}

// ================= VALU GEMM — round-1 VERBATIM (known-good) =================
constexpr int VTM = 64, VTN = 128, VKC = 64, VKSTR = VKC + 4;

template<int IN_MODE, int IN_SHIFT, int OUT_SHIFT, bool RES, bool OUT_BF16>
__global__ __launch_bounds__(256) void gemm_v(
    const void* __restrict__ Asrc, const float* __restrict__ st,
    const float* __restrict__ lng, const float* __restrict__ lnb,
    const float* __restrict__ W, const float* __restrict__ bias,
    const float* __restrict__ Rsrc, void* __restrict__ Out, int Ncols)
{
  __shared__ float As[VTM][VKSTR];
  __shared__ float Ws[VTN][VKSTR];
  const int tid = threadIdx.x;
  const int tx = tid & 15, ty = tid >> 4;
  const int ty4 = ty * 4;
  const int mtile = blockIdx.y * VTM;
  const int ntile = blockIdx.x * VTN;
  float acc[4][8];
  #pragma unroll
  for (int r = 0; r < 4; ++r)
    #pragma unroll
    for (int c = 0; c < 8; ++c) acc[r][c] = 0.f;

  for (int kc = 0; kc < DIM; kc += VKC) {
    #pragma unroll
    for (int it = 0; it < 4; ++it) {
      int idx = tid + it * 256;
      int m = idx >> 4;
      int k4 = (idx & 15) << 2;
      int gm = mtile + m;
      float4 a;
      if constexpr (IN_MODE == 0) {
        int src = (IN_SHIFT < 0) ? gm : win_map(gm, IN_SHIFT);
        a = *(const float4*)((const float*)Asrc + (size_t)src * DIM + kc + k4);
        float mu = st[2 * src], rs = st[2 * src + 1];
        int k = kc + k4;
        a.x = (a.x - mu) * rs * lng[k]     + lnb[k];
        a.y = (a.y - mu) * rs * lng[k + 1] + lnb[k + 1];
        a.z = (a.z - mu) * rs * lng[k + 2] + lnb[k + 2];
        a.w = (a.w - mu) * rs * lng[k + 3] + lnb[k + 3];
      } else {
        const uint32_t* ap = (const uint32_t*)((const uint16_t*)Asrc + (size_t)gm * DIM + kc + k4);
        uint32_t u0 = ap[0], u1 = ap[1];
        a.x = bflo(u0); a.y = bfhi(u0); a.z = bflo(u1); a.w = bfhi(u1);
      }
      *(float4*)&As[m][k4] = a;
    }
    #pragma unroll
    for (int it = 0; it < 8; ++it) {
      int idx = tid + it * 256;
      int n = idx >> 4;
      int k4 = (idx & 15) << 2;
      float4 w = *(const float4*)(W + (size_t)(ntile + n) * DIM + kc + k4);
      *(float4*)&Ws[n][k4] = w;
    }
    __syncthreads();
    #pragma unroll 4
    for (int k = 0; k < VKC; k += 2) {
      float2 a0 = *(const float2*)&As[ty4 + 0][k];
      float2 a1 = *(const float2*)&As[ty4 + 1][k];
      float2 a2 = *(const float2*)&As[ty4 + 2][k];
      float2 a3 = *(const float2*)&As[ty4 + 3][k];
      #pragma unroll
      for (int c = 0; c < 8; ++c) {
        float2 w = *(const float2*)&Ws[tx + 16 * c][k];
        acc[0][c] = fmaf(a0.x, w.x, acc[0][c]);
        acc[1][c] = fmaf(a1.x, w.x, acc[1][c]);
        acc[2][c] = fmaf(a2.x, w.x, acc[2][c]);
        acc[3][c] = fmaf(a3.x, w.x, acc[3][c]);
        acc[0][c] = fmaf(a0.y, w.y, acc[0][c]);
        acc[1][c] = fmaf(a1.y, w.y, acc[1][c]);
        acc[2][c] = fmaf(a2.y, w.y, acc[2][c]);
        acc[3][c] = fmaf(a3.y, w.y, acc[3][c]);
      }
    }
    __syncthreads();
  }
  float bb[8];
  #pragma unroll
  for (int c = 0; c < 8; ++c) bb[c] = bias[ntile + tx + 16 * c];
  #pragma unroll
  for (int r = 0; r < 4; ++r) {
    int gm = mtile + ty4 + r;
    int orow = (OUT_SHIFT < 0) ? gm : win_map(gm, OUT_SHIFT);
    #pragma unroll
    for (int c = 0; c < 8; ++c) {
      int gn = ntile + tx + 16 * c;
      float v = acc[r][c] + bb[c];
      if constexpr (RES) v += Rsrc[(size_t)orow * DIM + gn];
      if constexpr (OUT_BF16) ((uint16_t*)Out)[(size_t)gm * Ncols + gn] = bf16of(v);
      else                    ((float*)Out)[(size_t)orow * (size_t)Ncols + gn] = v;
    }
  }
}

// ================= MFMA GEMM (under test — used ONLY for qkv this round) =================
constexpr int MKC = 64, MKSTR = MKC + 8;

template<int IN_MODE, int IN_SHIFT, int OUT_SHIFT, bool RES, bool OUT_BF16>
__global__ __launch_bounds__(256) void gemm_m(
    const void* __restrict__ Asrc, const float* __restrict__ st,
    const float* __restrict__ lng, const float* __restrict__ lnb,
    const float* __restrict__ W, const float* __restrict__ bias,
    const float* Rsrc, void* Out, int Ncols)
{
  __shared__ __align__(16) uint16_t As[128][MKSTR];
  __shared__ __align__(16) uint16_t Ws[128][MKSTR];
  const int tid = threadIdx.x;
  const int lane = tid & 63;
  const int lanelow = lane & 15;
  const int quad = lane >> 4;
  const int wid = tid >> 6;
  const int wave_m = wid >> 1, wave_n = wid & 1;
  const int mtile = blockIdx.y * 128;
  const int ntile = blockIdx.x * 128;

  f32x4 acc[4][4];
  #pragma unroll
  for (int mt = 0; mt < 4; ++mt)
    #pragma unroll
    for (int nt = 0; nt < 4; ++nt) acc[mt][nt] = (f32x4){0.f, 0.f, 0.f, 0.f};

  for (int kc = 0; kc < DIM; kc += MKC) {
    #pragma unroll
    for (int it = 0; it < 8; ++it) {
      int idx = tid + it * 256;
      int m = idx >> 4;
      int k4 = (idx & 15) << 2;
      int gm = mtile + m;
      uint2 packed;
      if constexpr (IN_MODE == 0) {
        int src = (IN_SHIFT < 0) ? gm : win_map(gm, IN_SHIFT);
        float4 a = *(const float4*)((const float*)Asrc + (size_t)src * DIM + kc + k4);
        float mu = st[2 * src], rs = st[2 * src + 1];
        int k = kc + k4;
        a.x = (a.x - mu) * rs * lng[k]     + lnb[k];
        a.y = (a.y - mu) * rs * lng[k + 1] + lnb[k + 1];
        a.z = (a.z - mu) * rs * lng[k + 2] + lnb[k + 2];
        a.w = (a.w - mu) * rs * lng[k + 3] + lnb[k + 3];
        packed.x = bfpack(a.x, a.y);
        packed.y = bfpack(a.z, a.w);
      } else {
        packed = *(const uint2*)((const uint16_t*)Asrc + (size_t)gm * DIM + kc + k4);
      }
      *(uint2*)&As[m][k4] = packed;
    }
    #pragma unroll
    for (int it = 0; it < 8; ++it) {
      int idx = tid + it * 256;
      int n = idx >> 4;
      int k4 = (idx & 15) << 2;
      float4 w = *(const float4*)(W + (size_t)(ntile + n) * DIM + kc + k4);
      uint2 packed;
      packed.x = bfpack(w.x, w.y);
      packed.y = bfpack(w.z, w.w);
      *(uint2*)&Ws[n][k4] = packed;
    }
    __syncthreads();
    #pragma unroll
    for (int k0 = 0; k0 < MKC; k0 += 32) {
      short8 af[4], bf[4];
      #pragma unroll
      for (int mt = 0; mt < 4; ++mt)
        af[mt] = *(const short8*)&As[wave_m * 64 + mt * 16 + lanelow][k0 + quad * 8];
      #pragma unroll
      for (int nt = 0; nt < 4; ++nt)
        bf[nt] = *(const short8*)&Ws[wave_n * 64 + nt * 16 + lanelow][k0 + quad * 8];
      #pragma unroll
      for (int mt = 0; mt < 4; ++mt)
        #pragma unroll
        for (int nt = 0; nt < 4; ++nt)
          acc[mt][nt] = __builtin_amdgcn_mfma_f32_16x16x32_bf16(af[mt], bf[nt], acc[mt][nt], 0, 0, 0);
    }
    __syncthreads();
  }
  #pragma unroll
  for (int nt = 0; nt < 4; ++nt) {
    int col = ntile + wave_n * 64 + nt * 16 + lanelow;
    float bb = bias[col];
    #pragma unroll
    for (int mt = 0; mt < 4; ++mt) {
      #pragma unroll
      for (int r = 0; r < 4; ++r) {
        int gm = mtile + wave_m * 64 + mt * 16 + quad * 4 + r;
        float v = acc[mt][nt][r] + bb;
        if constexpr (OUT_BF16) {
          ((uint16_t*)Out)[(size_t)gm * Ncols + col] = bf16of(v);
        } else {
          int orow = (OUT_SHIFT < 0) ? gm : win_map(gm, OUT_SHIFT);
          if constexpr (RES) v += Rsrc[(size_t)orow * DIM + col];
          ((float*)Out)[(size_t)orow * (size_t)Ncols + col] = v;
        }
      }
    }
  }
}

// ================= attention — round-1 VERBATIM (known-good) =================
__global__ __launch_bounds__(64) void attn_k(const uint32_t* __restrict__ qkv32,
                                             const float* __restrict__ tbl,
                                             uint32_t* __restrict__ aw32)
{
  const int bid = blockIdx.x;
  const int w = bid >> 2, h = bid & 3;
  const int base = w * 49;
  const int lane = threadIdx.x;
  __shared__ float k_s[49 * 32];
  __shared__ float v_s[49 * 32];
  for (int p = lane; p < 784; p += 64) {
    int t = p >> 4, c2 = p & 15;
    size_t rowoff = (size_t)(base + t) * 192;
    uint32_t uk = qkv32[rowoff + 64  + h * 16 + c2];
    uint32_t uv = qkv32[rowoff + 128 + h * 16 + c2];
    k_s[t * 32 + 2 * c2]     = bflo(uk);
    k_s[t * 32 + 2 * c2 + 1] = bfhi(uk);
    v_s[t * 32 + 2 * c2]     = bflo(uv);
    v_s[t * 32 + 2 * c2 + 1] = bfhi(uv);
  }
  const int i = (lane < 49) ? lane : 48;
  float q[32];
  {
    const uint32_t* qrow = qkv32 + (size_t)(base + i) * 192 + h * 16;
    #pragma unroll
    for (int c2 = 0; c2 < 16; ++c2) {
      uint32_t u = qrow[c2];
      q[2 * c2]     = bflo(u) * 0.17677669529663689f;
      q[2 * c2 + 1] = bfhi(u) * 0.17677669529663689f;
    }
  }
  __syncthreads();
  const int yi = i / 7, xi = i - yi * 7;
  float s[49];
  #pragma unroll
  for (int j = 0; j < 49; ++j) {
    const int yj = j / 7, xj = j - yj * 7;
    const float* kr = &k_s[j * 32];
    float a0 = 0.f, a1 = 0.f, a2 = 0.f, a3 = 0.f;
    #pragma unroll
    for (int c = 0; c < 32; c += 4) {
      float4 kk = *(const float4*)(kr + c);
      a0 = fmaf(q[c],     kk.x, a0);
      a1 = fmaf(q[c + 1], kk.y, a1);
      a2 = fmaf(q[c + 2], kk.z, a2);
      a3 = fmaf(q[c + 3], kk.w, a3);
    }
    int ridx = (yi - yj + 6) * 13 + (xi - xj + 6);
    s[j] = (a0 + a1) + (a2 + a3) + tbl[ridx * 4 + h];
  }
  float mx = s[0];
  #pragma unroll
  for (int j = 1; j < 49; ++j) mx = fmaxf(mx, s[j]);
  float sum = 0.f;
  #pragma unroll
  for (int j = 0; j < 49; ++j) { s[j] = __expf(s[j] - mx); sum += s[j]; }
  float inv = 1.0f / sum;
  float o[32];
  #pragma unroll
  for (int c = 0; c < 32; ++c) o[c] = 0.f;
  #pragma unroll
  for (int j = 0; j < 49; ++j) {
    float sj = s[j] * inv;
    const float* vr = &v_s[j * 32];
    #pragma unroll
    for (int c = 0; c < 32; c += 4) {
      float4 vv = *(const float4*)(vr + c);
      o[c]     = fmaf(sj, vv.x, o[c]);
      o[c + 1] = fmaf(sj, vv.y, o[c + 1]);
      o[c + 2] = fmaf(sj, vv.z, o[c + 2]);
      o[c + 3] = fmaf(sj, vv.w, o[c + 3]);
    }
  }
  if (lane < 49) {
    uint32_t* dst = aw32 + (size_t)(base + i) * 64 + h * 16;
    #pragma unroll
    for (int c2 = 0; c2 < 16; ++c2) dst[c2] = bfpack(o[2 * c2], o[2 * c2 + 1]);
  }
}

extern "C" void kernel_launch(void* const* d_in, const int* in_sizes, int n_in,
                              void* d_out, int out_size, void* d_ws, size_t ws_size,
                              hipStream_t stream) {
  const float* x0    = (const float*)d_in[0];
  const float* ln1g  = (const float*)d_in[1];
  const float* ln1b  = (const float*)d_in[2];
  const float* wqkv1 = (const float*)d_in[3];
  const float* bqkv1 = (const float*)d_in[4];
  const float* wo1   = (const float*)d_in[5];
  const float* bo1   = (const float*)d_in[6];
  const float* tbl1  = (const float*)d_in[7];
  const float* ln2g  = (const float*)d_in[8];
  const float* ln2b  = (const float*)d_in[9];
  const float* wm1   = (const float*)d_in[10];
  const float* bm1   = (const float*)d_in[11];
  const float* ln3g  = (const float*)d_in[12];
  const float* ln3b  = (const float*)d_in[13];
  const float* wqkv2 = (const float*)d_in[14];
  const float* bqkv2 = (const float*)d_in[15];
  const float* wo2   = (const float*)d_in[16];
  const float* bo2   = (const float*)d_in[17];
  const float* tbl2  = (const float*)d_in[18];
  const float* ln4g  = (const float*)d_in[19];
  const float* ln4b  = (const float*)d_in[20];
  const float* wm2   = (const float*)d_in[21];
  const float* bm2   = (const float*)d_in[22];

  char* ws = (char*)d_ws;
  size_t off = 0;
  float* st = (float*)(ws + off);         off += (size_t)NTOK * 2 * sizeof(float);
  off = (off + 255) & ~(size_t)255;
  uint16_t* qkvb = (uint16_t*)(ws + off); off += (size_t)NTOK * 384 * sizeof(uint16_t);
  uint16_t* awb  = (uint16_t*)(ws + off); off += (size_t)NTOK * 128 * sizeof(uint16_t);
  float* x2      = (float*)(ws + off);    off += (size_t)NTOK * 128 * sizeof(float);
  if (ws_size < off) return;
  float* x1 = (float*)d_out;

  dim3 blk(256);
  dim3 sgrid(NTOK / 4);
  dim3 g3m(3, 1568);        // MFMA qkv tiles (128-row)
  dim3 g1v(1, 3136);        // VALU tiles (64-row)
  dim3 agrid(16384);

  // block 1: W-MSA — qkv via MFMA (under test), everything else r1-verbatim VALU
  stats_k<<<sgrid, blk, 0, stream>>>(x0, st);
  gemm_m<0, 0, -1, false, true><<<g3m, blk, 0, stream>>>(x0, st, ln1g, ln1b, wqkv1, bqkv1, nullptr, qkvb, 384);
  attn_k<<<agrid, dim3(64), 0, stream>>>((const uint32_t*)qkvb, tbl1, (uint32_t*)awb);
  gemm_v<1, -1, -1, true, false><<<g1v, blk, 0, stream>>>(awb, nullptr, nullptr, nullptr, wo1, bo1, x0, x1, 128);
  // mlp1 via VALU
  stats_k<<<sgrid, blk, 0, stream>>>(x1, st);
  gemm_v<0, -1, -1, true, false><<<g1v, blk, 0, stream>>>(x1, st, ln2g, ln2b, wm1, bm1, x1, x2, 128);
  // block 2: SW-MSA — qkv via MFMA (under test)
  stats_k<<<sgrid, blk, 0, stream>>>(x2, st);
  gemm_m<0, 3, -1, false, true><<<g3m, blk, 0, stream>>>(x2, st, ln3g, ln3b, wqkv2, bqkv2, nullptr, qkvb, 384);
  attn_k<<<agrid, dim3(64), 0, stream>>>((const uint32_t*)qkvb, tbl2, (uint32_t*)awb);
  gemm_v<1, -1, 3, true, false><<<g1v, blk, 0, stream>>>(awb, nullptr, nullptr, nullptr, wo2, bo2, x2, x2, 128);
  // mlp2 via VALU (r1-verbatim)
  stats_k<<<sgrid, blk, 0, stream>>>(x2, st);
  gemm_v<0, -1, -1, false, false><<<g1v, blk, 0, stream>>>(x2, st, ln4g, ln4b, wm2, bm2, nullptr, d_out, 128);
}